// Round 9
// baseline (755.186 us; speedup 1.0000x reference)
//
#include <hip/hip_runtime.h>
#include <stdint.h>

#define B_  256
#define T_  512
#define H_  128
#define NSW 6

typedef __bf16 bf2_t __attribute__((ext_vector_type(2)));
typedef __attribute__((address_space(3))) uint4 u4_lds;

#define AS1C(p) ((const __attribute__((address_space(1))) void*)(p))
#define AS3C(p) ((__attribute__((address_space(3))) void*)(p))

// float -> bf16 round-to-nearest-even
__device__ __forceinline__ unsigned short f2bf(float f){
  unsigned u = __float_as_uint(f);
  unsigned r = u + 0x7FFFu + ((u >> 16) & 1u);
  return (unsigned short)(r >> 16);
}
__device__ __forceinline__ unsigned pack2(float a, float b){
  return (unsigned)f2bf(a) | ((unsigned)f2bf(b) << 16);
}
__device__ __forceinline__ float b2f(unsigned short u){
  return __uint_as_float((unsigned)u << 16);
}

// acc += dot2(bf16x2 w, bf16x2 h)
__device__ __forceinline__ float dot2bf(unsigned wpair, unsigned hpair, float acc){
  return __builtin_amdgcn_fdot2_f32_bf16(__builtin_bit_cast(bf2_t, wpair),
                                         __builtin_bit_cast(bf2_t, hpair), acc, false);
}

// LDS-only barrier: drains lgkmcnt but NOT vmcnt -> in-flight DMAs survive.
__device__ __forceinline__ void lds_barrier(){
  asm volatile("s_waitcnt lgkmcnt(0)\ns_barrier" ::: "memory");
}

// Read one 8-KB chunk header: 8 x ds_read_b128 at addr + j*1024.
// vmcnt(8) first: waits for the OLDEST 8-DMA batch (this chunk's fill),
// leaves the newer 8 in flight. Opaque to SIInsertWaitcnts.
__device__ __forceinline__ void rd8(unsigned addr, uint4& w0, uint4& w1,
                                    uint4& w2, uint4& w3, uint4& w4,
                                    uint4& w5, uint4& w6, uint4& w7){
  asm volatile(
    "s_waitcnt vmcnt(8)\n\t"
    "ds_read_b128 %0, %8\n\t"
    "ds_read_b128 %1, %8 offset:1024\n\t"
    "ds_read_b128 %2, %8 offset:2048\n\t"
    "ds_read_b128 %3, %8 offset:3072\n\t"
    "ds_read_b128 %4, %8 offset:4096\n\t"
    "ds_read_b128 %5, %8 offset:5120\n\t"
    "ds_read_b128 %6, %8 offset:6144\n\t"
    "ds_read_b128 %7, %8 offset:7168\n\t"
    "s_waitcnt lgkmcnt(0)"
    : "=&v"(w0), "=&v"(w1), "=&v"(w2), "=&v"(w3),
      "=&v"(w4), "=&v"(w5), "=&v"(w6), "=&v"(w7)
    : "v"(addr)
    : "memory");
}

// Pack for DMA layout: uint4 idx = (g*6+s)*2048 + hf*1024 + q*512 + m*64 + l
// holds bf16 of W_g[s][row = hf*64+l][k = q*64 + 8m .. +7]
__global__ __launch_bounds__(256) void pack_weights(const float* __restrict__ Wr,
                                                    const float* __restrict__ Wz,
                                                    const float* __restrict__ Wn,
                                                    uint4* __restrict__ dst){
  int idx = blockIdx.x * 256 + threadIdx.x;
  if (idx >= 3 * NSW * 2048) return;
  int l  = idx & 63;
  int m  = (idx >> 6) & 7;
  int q  = (idx >> 9) & 1;
  int hf = (idx >> 10) & 1;
  int gs = idx >> 11;           // g*6+s
  int s  = gs % NSW;
  int g  = gs / NSW;
  const float* W = (g == 0) ? Wr : (g == 1) ? Wz : Wn;
  const float* src = W + (size_t)s * (H_*H_) + (size_t)(hf*64 + l) * H_ + q*64 + m*8;
  uint4 o;
  o.x = pack2(src[0], src[1]);
  o.y = pack2(src[2], src[3]);
  o.z = pack2(src[4], src[5]);
  o.w = pack2(src[6], src[7]);
  dst[idx] = o;
}

// 384 threads = 6 waves. wave w: gate g = w>>1, row-half hf = w&1.
// lane l -> output row i = hf*64+l of gate g. Weights stream via
// global_load_lds into a per-wave 3-slot ring (8 KB slots, 2 chunks/step).
__global__ __launch_bounds__(384, 1) void gru_run(const float* __restrict__ stim,
    const int*   __restrict__ swid,  const float* __restrict__ mask,
    const float* __restrict__ Win,   const float* __restrict__ binp,
    const float* __restrict__ b_hr,  const float* __restrict__ b_hz, const float* __restrict__ b_hn,
    const float* __restrict__ Wo,    const float* __restrict__ bo,
    const uint4* __restrict__ Wpk,   float* __restrict__ out)
{
  __shared__ uint4          ringA[9216];    // 147456 B: 6 waves x 3 slots x 512 uint4
  __shared__ uint4          s_stim2[T_];    // 8192 B: 8 bf16 per step
  __shared__ unsigned short s_bias[3*NSW*H_]; // 4608 B bf16 [g][s][i]
  __shared__ unsigned short s_sid[T_];      // 1024 B
  __shared__ unsigned short s_mask[T_];     // 1024 B bf16
  __shared__ float          s_h[H_];        // 512 B fp32 h (single buffer)
  __shared__ unsigned       s_hb[64];       // 256 B h as bf16 pairs
  __shared__ unsigned short s_rz[2*H_];     // 512 B bf16 r,z

  const int b   = blockIdx.x;
  const int tid = threadIdx.x;
  const int w   = tid >> 6;
  const int l   = tid & 63;
  const int g   = w >> 1;
  const int hf  = w & 1;
  const int i   = hf * 64 + l;
  const int orow = g * H_ + i;

  // ---- init LDS ----
  for (int k = tid; k < T_; k += 384){
    const float* sp = stim + (size_t)b * T_ * 8 + (size_t)k * 8;
    uint4 o;
    o.x = pack2(sp[0], sp[1]); o.y = pack2(sp[2], sp[3]);
    o.z = pack2(sp[4], sp[5]); o.w = pack2(sp[6], sp[7]);
    s_stim2[k] = o;
    s_mask[k] = f2bf(mask[(size_t)b * T_ + k]);
    int ss = swid[(size_t)b * T_ + k];
    s_sid[k] = (unsigned short)(ss < 0 ? 0 : (ss > NSW - 1 ? NSW - 1 : ss));
  }
  for (int k = tid; k < 3 * NSW * H_; k += 384){
    int gg = k / (NSW * H_); int rr = k % (NSW * H_);
    const float* bp = (gg == 0) ? b_hr : (gg == 1) ? b_hz : b_hn;
    s_bias[k] = f2bf(bp[rr]);
  }
  if (tid < H_) s_h[tid] = 0.f;
  if (tid < 64) s_hb[tid] = 0u;

  // per-thread constants
  unsigned winp[4];
  #pragma unroll
  for (int e = 0; e < 4; ++e)
    winp[e] = pack2(Win[(size_t)orow * 8 + 2*e], Win[(size_t)orow * 8 + 2*e + 1]);
  const float binr = binp[orow];

  float wo_a = 0.f, wo_b = 0.f, bo_r = 0.f;
  const int kk = (w == 3) ? 1 : 0;
  if (g == 1){
    wo_a = Wo[kk * H_ + l];
    wo_b = Wo[kk * H_ + 64 + l];
    bo_r = bo[kk];
  }

  u4_lds* rA = (u4_lds*)ringA;
  const unsigned ring_base = (unsigned)(unsigned long long)rA;
  const unsigned wl_base   = ring_base + (unsigned)w * 24576u + (unsigned)l * 16u;
  const uint4* gmat = Wpk + (size_t)hf * 1024 + l;   // + (g*6+s)*2048 + q*512 + m*64
  float* outp = out + (size_t)b * T_ * 2;

  __syncthreads();

  int sc = __builtin_amdgcn_readfirstlane((int)s_sid[0]);
  int sn = __builtin_amdgcn_readfirstlane((int)s_sid[1]);

  // prologue: DMA step-0 chunks into slots 0,1
  {
    const uint4* gp0 = gmat + (size_t)(g * NSW + sc) * 2048;
    u4_lds* lp0 = rA + w * 1536;
    #pragma unroll
    for (int m = 0; m < 8; ++m)
      __builtin_amdgcn_global_load_lds(AS1C(gp0 + m*64), AS3C(lp0 + m*64), 16, 0, 0);
    const uint4* gp1 = gp0 + 512;
    u4_lds* lp1 = lp0 + 512;
    #pragma unroll
    for (int m = 0; m < 8; ++m)
      __builtin_amdgcn_global_load_lds(AS1C(gp1 + m*64), AS3C(lp1 + m*64), 16, 0, 0);
  }

  int r0 = 0;
  #pragma unroll 1
  for (int t = 0; t < T_; ++t){
    // ---- small LDS reads (distinct objects: no DMA-alias waits) ----
    unsigned hp = s_hb[l];
    uint4 sp = s_stim2[t];
    float bsc = b2f(s_bias[g * (NSW*H_) + sc * H_ + i]);
    int tn2 = (t + 2 < T_) ? t + 2 : T_ - 1;
    int snl = (int)s_sid[tn2];

    // input projection (bf16 dot2)
    float x = binr;
    x = dot2bf(winp[0], sp.x, x);
    x = dot2bf(winp[1], sp.y, x);
    x = dot2bf(winp[2], sp.z, x);
    x = dot2bf(winp[3], sp.w, x);

    const int sl1 = (r0 + 1 >= 3) ? r0 - 2 : r0 + 1;
    const int sl2 = (r0 + 2 >= 3) ? r0 - 1 : r0 + 2;

    float acc = 0.f;
    // ---- chunk q0 (slot r0): k in [0,64) ----
    {
      uint4 w0,w1,w2,w3,w4,w5,w6,w7;
      rd8(wl_base + (unsigned)r0 * 8192u, w0,w1,w2,w3,w4,w5,w6,w7);
      const uint4 wv[8] = {w0,w1,w2,w3,w4,w5,w6,w7};
      #pragma unroll
      for (int j = 0; j < 8; ++j){
        unsigned h0 = (unsigned)__builtin_amdgcn_readlane((int)hp, 4*j + 0);
        unsigned h1 = (unsigned)__builtin_amdgcn_readlane((int)hp, 4*j + 1);
        unsigned h2 = (unsigned)__builtin_amdgcn_readlane((int)hp, 4*j + 2);
        unsigned h3 = (unsigned)__builtin_amdgcn_readlane((int)hp, 4*j + 3);
        acc = dot2bf(wv[j].x, h0, acc);
        acc = dot2bf(wv[j].y, h1, acc);
        acc = dot2bf(wv[j].z, h2, acc);
        acc = dot2bf(wv[j].w, h3, acc);
      }
    }
    // DMA (t+1, q0) -> slot sl2 (free since last step)
    {
      const uint4* gp = gmat + (size_t)(g * NSW + sn) * 2048;
      u4_lds* lp = rA + w * 1536 + sl2 * 512;
      #pragma unroll
      for (int m = 0; m < 8; ++m)
        __builtin_amdgcn_global_load_lds(AS1C(gp + m*64), AS3C(lp + m*64), 16, 0, 0);
    }
    // ---- chunk q1 (slot sl1): k in [64,128) ----
    {
      uint4 w0,w1,w2,w3,w4,w5,w6,w7;
      rd8(wl_base + (unsigned)sl1 * 8192u, w0,w1,w2,w3,w4,w5,w6,w7);
      const uint4 wv[8] = {w0,w1,w2,w3,w4,w5,w6,w7};
      #pragma unroll
      for (int j = 0; j < 8; ++j){
        unsigned h0 = (unsigned)__builtin_amdgcn_readlane((int)hp, 32 + 4*j + 0);
        unsigned h1 = (unsigned)__builtin_amdgcn_readlane((int)hp, 32 + 4*j + 1);
        unsigned h2 = (unsigned)__builtin_amdgcn_readlane((int)hp, 32 + 4*j + 2);
        unsigned h3 = (unsigned)__builtin_amdgcn_readlane((int)hp, 32 + 4*j + 3);
        acc = dot2bf(wv[j].x, h0, acc);
        acc = dot2bf(wv[j].y, h1, acc);
        acc = dot2bf(wv[j].z, h2, acc);
        acc = dot2bf(wv[j].w, h3, acc);
      }
    }
    // DMA (t+1, q1) -> slot r0 (just consumed)
    {
      const uint4* gp = gmat + (size_t)(g * NSW + sn) * 2048 + 512;
      u4_lds* lp = rA + w * 1536 + r0 * 512;
      #pragma unroll
      for (int m = 0; m < 8; ++m)
        __builtin_amdgcn_global_load_lds(AS1C(gp + m*64), AS3C(lp + m*64), 16, 0, 0);
    }

    float hrec = acc + bsc;
    if (w < 4){   // gates r (g0) and z (g1): sigmoid
      float v = 1.f / (1.f + __expf(-(x + hrec)));
      s_rz[g * H_ + i] = f2bf(v);
    }
    lds_barrier();   // B1

    if (g == 2){
      float r = b2f(s_rz[i]);
      float z = b2f(s_rz[H_ + i]);
      float e = __expf(2.f * (x + r * hrec));
      float n = 1.f - 2.f / (e + 1.f);
      float hprev = s_h[i];
      float hnew  = (1.f - z) * n + z * hprev;
      float mt    = b2f(s_mask[t]);
      float ho    = mt * hnew + (1.f - mt) * hprev;
      s_h[i] = ho;
      ((unsigned short*)s_hb)[i] = f2bf(ho);
    }
    lds_barrier();   // B2

    if (g == 1){
      float p = wo_a * s_h[l] + wo_b * s_h[64 + l];
      p += __shfl_down(p, 32); p += __shfl_down(p, 16); p += __shfl_down(p, 8);
      p += __shfl_down(p, 4);  p += __shfl_down(p, 2);  p += __shfl_down(p, 1);
      if (l == 0) outp[t * 2 + kk] = p + bo_r;
    }

    sc = sn;
    sn = __builtin_amdgcn_readfirstlane(snl);
    r0 = (r0 + 2 >= 3) ? r0 - 1 : r0 + 2;
  }
}

extern "C" void kernel_launch(void* const* d_in, const int* in_sizes, int n_in,
                              void* d_out, int out_size, void* d_ws, size_t ws_size,
                              hipStream_t stream) {
  const float* stim = (const float*)d_in[0];
  const int*   swid = (const int*)  d_in[1];
  const float* mask = (const float*)d_in[2];
  const float* Win  = (const float*)d_in[3];
  const float* binp = (const float*)d_in[4];
  const float* Whr  = (const float*)d_in[5];
  const float* Whz  = (const float*)d_in[6];
  const float* Whn  = (const float*)d_in[7];
  const float* bhr  = (const float*)d_in[8];
  const float* bhz  = (const float*)d_in[9];
  const float* bhn  = (const float*)d_in[10];
  const float* Wo   = (const float*)d_in[11];
  const float* bo   = (const float*)d_in[12];

  uint4* wpk = (uint4*)d_ws;   // 589824 bytes used

  pack_weights<<<144, 256, 0, stream>>>(Whr, Whz, Whn, wpk);
  gru_run<<<B_, 384, 0, stream>>>(stim, swid, mask, Win, binp,
                                  bhr, bhz, bhn, Wo, bo, wpk, (float*)d_out);
}

// Round 10
// 669.472 us; speedup vs baseline: 1.1280x; 1.1280x over previous
//
#include <hip/hip_runtime.h>
#include <stdint.h>

#define B_  256
#define T_  512
#define H_  128
#define NSW 6

typedef __bf16 bf2_t __attribute__((ext_vector_type(2)));

// float -> bf16 round-to-nearest-even
__device__ __forceinline__ unsigned short f2bf(float f){
  unsigned u = __float_as_uint(f);
  unsigned r = u + 0x7FFFu + ((u >> 16) & 1u);
  return (unsigned short)(r >> 16);
}

// acc += dot2(bf16x2 w, bf16x2 h)
__device__ __forceinline__ float dot2bf(unsigned wpair, unsigned hpair, float acc){
#if __has_builtin(__builtin_amdgcn_fdot2_f32_bf16)
  return __builtin_amdgcn_fdot2_f32_bf16(__builtin_bit_cast(bf2_t, wpair),
                                         __builtin_bit_cast(bf2_t, hpair), acc, false);
#else
  asm("v_dot2_f32_bf16 %0, %1, %2, %0" : "+v"(acc) : "v"(wpair), "v"(hpair));
  return acc;
#endif
}

// LDS-only barrier: drains lgkmcnt but NOT vmcnt -> weight prefetch stays in flight.
__device__ __forceinline__ void lds_barrier(){
  asm volatile("s_waitcnt lgkmcnt(0)\ns_barrier" ::: "memory");
}

// Pack weights: dst[(g*6+s)*2048 + j8*128 + i] = uint4 of bf16 W_g[s][i][8*j8+0..7]
__global__ __launch_bounds__(256) void pack_weights(const float* __restrict__ Wr,
                                                    const float* __restrict__ Wz,
                                                    const float* __restrict__ Wn,
                                                    uint4* __restrict__ dst){
  int idx = blockIdx.x * 256 + threadIdx.x;
  if (idx >= 3 * NSW * 2048) return;
  int g  = idx / (NSW * 2048);
  int r0 = idx % (NSW * 2048);
  int s  = r0 / 2048;
  int q  = r0 % 2048;
  int j8 = q / 128;
  int i  = q % 128;
  const float* W = (g == 0) ? Wr : (g == 1) ? Wz : Wn;
  const float* src = W + (size_t)s * (H_*H_) + (size_t)i * H_ + 8 * j8;
  uint4 o;
  o.x = (unsigned)f2bf(src[0]) | ((unsigned)f2bf(src[1]) << 16);
  o.y = (unsigned)f2bf(src[2]) | ((unsigned)f2bf(src[3]) << 16);
  o.z = (unsigned)f2bf(src[4]) | ((unsigned)f2bf(src[5]) << 16);
  o.w = (unsigned)f2bf(src[6]) | ((unsigned)f2bf(src[7]) << 16);
  dst[idx] = o;
}

// NOTE: Wpk and out are deliberately NOT const/__restrict__: the possible
// aliasing with the per-step out-stores makes the weight loads
// non-invariant -> not rematerializable by RA, cannot cross the barrier
// asm memory clobbers -> the early-issued loads MUST stay register-resident
// until their step-t+1 use (real double buffer, fine-grained vmcnt waits).
__global__ __launch_bounds__(384, 1) void gru_run(const float* __restrict__ stim,
    const int*   __restrict__ swid,  const float* __restrict__ mask,
    const float* __restrict__ Win,   const float* __restrict__ binp,
    const float* __restrict__ b_hr,  const float* __restrict__ b_hz, const float* __restrict__ b_hn,
    const float* __restrict__ Wo,    const float* __restrict__ bo,
    uint4* Wpk,   float* out)
{
  const int b    = blockIdx.x;
  const int tid  = threadIdx.x;
  const int g    = tid >> 7;
  const int i    = tid & 127;
  const int lane = tid & 63;

  __shared__ float    s_stim[T_ * 8];     // 16 KB
  __shared__ float    s_mask[T_];         //  2 KB
  __shared__ int      s_sid[T_];          //  2 KB
  __shared__ float    s_b[3 * NSW * H_];  //  9 KB
  __shared__ float    s_r[H_];
  __shared__ float    s_z[H_];
  __shared__ float    s_h[2][H_];         // fp32 h state
  __shared__ unsigned s_hb[2][64];        // h packed as bf16 pairs

  // ---- preload chain-local data ----
  for (int k = tid; k < T_ * 8; k += 384) s_stim[k] = stim[(size_t)b * T_ * 8 + k];
  for (int k = tid; k < T_; k += 384){
    s_mask[k] = mask[(size_t)b * T_ + k];
    int ss = swid[(size_t)b * T_ + k];
    s_sid[k] = ss < 0 ? 0 : (ss > NSW - 1 ? NSW - 1 : ss);
  }
  for (int k = tid; k < NSW * H_; k += 384){
    s_b[k]                = b_hr[k];
    s_b[NSW * H_ + k]     = b_hz[k];
    s_b[2 * NSW * H_ + k] = b_hn[k];
  }
  if (tid < H_) s_h[0][tid] = 0.f;
  if (tid < 64) s_hb[0][tid] = 0u;

  float winr[8];
  #pragma unroll
  for (int s2 = 0; s2 < 8; ++s2) winr[s2] = Win[tid * 8 + s2];
  const float binr = binp[tid];

  float wo_a = 0.f, wo_b = 0.f, bo_r = 0.f;
  const int kk = (tid >= 192 && tid < 256) ? 1 : 0;
  if (g == 1){
    wo_a = Wo[kk * H_ + lane];
    wo_b = Wo[kk * H_ + 64 + lane];
    bo_r = bo[kk];
  }

  uint4* gbase = Wpk + (size_t)g * (NSW * 2048) + i;
  float* outp = out + (size_t)b * T_ * 2;

  __syncthreads();

  // sid pipeline carried in SGPRs: sc = sid[t], sn = sid[t+1]
  int sc = __builtin_amdgcn_readfirstlane(s_sid[0]);
  int sn = __builtin_amdgcn_readfirstlane(s_sid[1]);

  // preload step-0 weights (sid = sc)
  uint4 WA[16], WB[16];
  {
    uint4* wp = gbase + (size_t)sc * 2048;
    #pragma unroll
    for (int j = 0; j < 16; ++j) WA[j] = wp[j * 128];
  }

#define STEP(t, WC, WN) do {                                                   \
    const int cur = (t) & 1, nxt = cur ^ 1;                                    \
    /* issue next-step prefetch first: address ready (sn in SGPR). These are */\
    /* ordinary (may-alias) loads now: they cannot sink across the barrier   */\
    /* asms below and cannot be rematerialized at their step-t+1 use.        */\
    { uint4* wp = gbase + (size_t)sn * 2048;                                   \
      _Pragma("unroll")                                                        \
      for (int j = 0; j < 16; ++j) WN[j] = wp[j * 128]; }                      \
    __builtin_amdgcn_sched_barrier(0);                                         \
    int tn2 = ((t) + 2 < T_) ? (t) + 2 : T_ - 1;                               \
    int snl = s_sid[tn2];                                                      \
    unsigned hp = s_hb[cur][lane];                                             \
    float4 sa = *reinterpret_cast<const float4*>(&s_stim[(t) * 8]);            \
    float4 sb = *reinterpret_cast<const float4*>(&s_stim[(t) * 8 + 4]);        \
    float x = binr + winr[0]*sa.x + winr[1]*sa.y + winr[2]*sa.z + winr[3]*sa.w \
                   + winr[4]*sb.x + winr[5]*sb.y + winr[6]*sb.z + winr[7]*sb.w;\
    float a0 = 0.f, a1 = 0.f, a2 = 0.f, a3 = 0.f;                              \
    _Pragma("unroll")                                                          \
    for (int j8 = 0; j8 < 16; ++j8){                                           \
      uint4 w = WC[j8];                                                        \
      unsigned h0 = (unsigned)__builtin_amdgcn_readlane((int)hp, 4*j8 + 0);    \
      unsigned h1 = (unsigned)__builtin_amdgcn_readlane((int)hp, 4*j8 + 1);    \
      unsigned h2 = (unsigned)__builtin_amdgcn_readlane((int)hp, 4*j8 + 2);    \
      unsigned h3 = (unsigned)__builtin_amdgcn_readlane((int)hp, 4*j8 + 3);    \
      a0 = dot2bf(w.x, h0, a0);                                                \
      a1 = dot2bf(w.y, h1, a1);                                                \
      a2 = dot2bf(w.z, h2, a2);                                                \
      a3 = dot2bf(w.w, h3, a3);                                                \
    }                                                                          \
    float acc = ((a0 + a1) + (a2 + a3)) + s_b[g * (NSW*H_) + sc * H_ + i];     \
    if (g == 0)      s_r[i] = 1.f / (1.f + __expf(-(x + acc)));                \
    else if (g == 1) s_z[i] = 1.f / (1.f + __expf(-(x + acc)));                \
    lds_barrier();                                                             \
    if (g == 2){                                                               \
      float r = s_r[i], z = s_z[i], hprev = s_h[cur][i];                       \
      float e = __expf(2.f * (x + r * acc));                                   \
      float n = 1.f - 2.f / (e + 1.f);                                         \
      float hnew = (1.f - z) * n + z * hprev;                                  \
      float mt = s_mask[(t)];                                                  \
      float ho = mt * hnew + (1.f - mt) * hprev;                               \
      s_h[nxt][i] = ho;                                                        \
      ((unsigned short*)s_hb[nxt])[i] = f2bf(ho);                              \
    }                                                                          \
    lds_barrier();                                                             \
    if (g == 1){                                                               \
      float p = wo_a * s_h[nxt][lane] + wo_b * s_h[nxt][64 + lane];            \
      p += __shfl_down(p, 32); p += __shfl_down(p, 16); p += __shfl_down(p, 8);\
      p += __shfl_down(p, 4);  p += __shfl_down(p, 2);  p += __shfl_down(p, 1);\
      if (lane == 0) outp[(t) * 2 + kk] = p + bo_r;                            \
    }                                                                          \
    sc = sn;                                                                   \
    sn = __builtin_amdgcn_readfirstlane(snl);                                  \
  } while (0)

  #pragma unroll 1
  for (int t = 0; t < T_; t += 2){
    STEP(t,     WA, WB);
    STEP(t + 1, WB, WA);
  }
#undef STEP
}

extern "C" void kernel_launch(void* const* d_in, const int* in_sizes, int n_in,
                              void* d_out, int out_size, void* d_ws, size_t ws_size,
                              hipStream_t stream) {
  const float* stim = (const float*)d_in[0];
  const int*   swid = (const int*)  d_in[1];
  const float* mask = (const float*)d_in[2];
  const float* Win  = (const float*)d_in[3];
  const float* binp = (const float*)d_in[4];
  const float* Whr  = (const float*)d_in[5];
  const float* Whz  = (const float*)d_in[6];
  const float* Whn  = (const float*)d_in[7];
  const float* bhr  = (const float*)d_in[8];
  const float* bhz  = (const float*)d_in[9];
  const float* bhn  = (const float*)d_in[10];
  const float* Wo   = (const float*)d_in[11];
  const float* bo   = (const float*)d_in[12];

  uint4* wpk = (uint4*)d_ws;   // 589824 bytes used

  pack_weights<<<144, 256, 0, stream>>>(Whr, Whz, Whn, wpk);
  gru_run<<<B_, 384, 0, stream>>>(stim, swid, mask, Win, binp,
                                  bhr, bhz, bhn, Wo, bo, wpk, (float*)d_out);
}